// Round 15
// baseline (104.690 us; speedup 1.0000x reference)
//
#include <hip/hip_runtime.h>
#include <hip/hip_bf16.h>
#include <type_traits>

typedef __bf16 bf16_t;
typedef __bf16 bf16x4 __attribute__((ext_vector_type(4)));
typedef __bf16 bf16x8 __attribute__((ext_vector_type(8)));
typedef float  f32x4  __attribute__((ext_vector_type(4)));

__device__ __forceinline__ f32x4 mfma16(bf16x8 a, bf16x8 b, f32x4 c) {
  return __builtin_amdgcn_mfma_f32_16x16x32_bf16(a, b, c, 0, 0, 0);
}

static constexpr int NB = 8;
static constexpr int LQ = 1024;
static constexpr int LKk = 1024;
static constexpr int DMODEL = 512;
static constexpr int NH = 8;
static constexpr int DKH = 64;
static constexpr int MROWS = NB * LQ;   // 8192
static constexpr int MWORDS = NB * LQ * (LKk / 64);  // 131072 u64 words
#define KSCALE 0.1803368801111204f

// swizzled byte offset for [R][128B] row-major LDS tiles (G4 XOR swizzle)
__device__ __forceinline__ int swz(int row, int byte) {
  return row * 128 + (byte ^ ((row & 7) << 4));
}

// ------- mask bit-pack: one u64 word per THREAD, 16 independent int4 loads --
__global__ __launch_bounds__(256)
void mask_pack(const int* __restrict__ mask, unsigned long long* __restrict__ mpk) {
  const int wd = blockIdx.x * 256 + threadIdx.x;
  const int4* base = reinterpret_cast<const int4*>(mask + (size_t)wd * 64);
  unsigned long long bits = 0;
  #pragma unroll
  for (int i = 0; i < 16; ++i) {
    int4 v = base[i];
    bits |= (unsigned long long)(v.x != 0) << (4 * i);
    bits |= (unsigned long long)(v.y != 0) << (4 * i + 1);
    bits |= (unsigned long long)(v.z != 0) << (4 * i + 2);
    bits |= (unsigned long long)(v.w != 0) << (4 * i + 3);
  }
  mpk[wd] = bits;
}

// ------- one-time weight transpose+convert: W f32 [K][N] -> Wt bf16 [N][K] --
__device__ __forceinline__ void wt_tile(const float* __restrict__ W, bf16_t* __restrict__ Wt,
                                        int K, int N, int kt, int nt, int t) {
  __shared__ bf16_t T[64][72];
  const int k0 = kt * 64, n0 = nt * 64;
  const int kr = t >> 2, c0 = (t & 3) * 16;
  const float4* src = reinterpret_cast<const float4*>(W + (size_t)(k0 + kr) * N + n0 + c0);
  #pragma unroll
  for (int j = 0; j < 4; ++j) {
    float4 f = src[j];
    T[c0 + j * 4 + 0][kr] = (bf16_t)f.x;
    T[c0 + j * 4 + 1][kr] = (bf16_t)f.y;
    T[c0 + j * 4 + 2][kr] = (bf16_t)f.z;
    T[c0 + j * 4 + 3][kr] = (bf16_t)f.w;
  }
  __syncthreads();
  const int nr = t >> 2, kc0 = (t & 3) * 16;
  bf16_t* dst = Wt + (size_t)(n0 + nr) * K + k0 + kc0;
  #pragma unroll
  for (int j = 0; j < 2; ++j)
    *reinterpret_cast<bf16x8*>(dst + j * 8) =
        *reinterpret_cast<const bf16x8*>(&T[nr][kc0 + j * 8]);
}

__global__ __launch_bounds__(256)
void weight_prep(const float* __restrict__ Wq, const float* __restrict__ Wk,
                 const float* __restrict__ Wv, const float* __restrict__ Wo,
                 bf16_t* __restrict__ Wtq, bf16_t* __restrict__ Wtk,
                 bf16_t* __restrict__ Wtv, bf16_t* __restrict__ Wto) {
  const int bidx = blockIdx.x, t = threadIdx.x;
  if (bidx < 32)        wt_tile(Wq, Wtq, 256, 512, bidx >> 3, bidx & 7, t);
  else if (bidx < 64)   wt_tile(Wk, Wtk, 256, 512, (bidx - 32) >> 3, bidx & 7, t);
  else if (bidx < 96)   wt_tile(Wv, Wtv, 256, 512, (bidx - 64) >> 3, bidx & 7, t);
  else                  wt_tile(Wo, Wto, 512, 512, (bidx - 96) >> 3, bidx & 7, t);
}

// ---- GEMM v3: BM=128, BN=64, BK=64; wave owns 32x64, acc[2][4] ----
// C[M,512] = postscale * act(A @ Wt^T + bias)
template<int K, bool RELU, typename AT, typename OT>
__global__ __launch_bounds__(256)
void gemm_bias_act(const AT* __restrict__ A, const bf16_t* __restrict__ Wt,
                   const float* __restrict__ bias, OT* __restrict__ C,
                   float postscale)
{
  constexpr int N = 512;
  __shared__ alignas(16) char Alds[128 * 128];   // 16 KB
  __shared__ alignas(16) char Wlds[64 * 128];    //  8 KB
  const int t = threadIdx.x;
  const int l = t & 63, w = t >> 6;
  const int xcd = blockIdx.x & 7, idx = blockIdx.x >> 3;
  const int m0 = (xcd * 8 + (idx >> 3)) * 128, n0 = (idx & 7) * 64;

  f32x4 acc[2][4] = {};
  for (int k0 = 0; k0 < K; k0 += 64) {
    __syncthreads();
    // stage A tile [128 m][64 k]
    if constexpr (std::is_same<AT, float>::value) {
      const int row = t >> 1, c0 = (t & 1) * 32;
      const float4* ap = reinterpret_cast<const float4*>(A + (size_t)(m0 + row) * K + k0 + c0);
      #pragma unroll
      for (int j = 0; j < 8; ++j) {
        float4 f = ap[j];
        bf16x4 o = { (bf16_t)f.x, (bf16_t)f.y, (bf16_t)f.z, (bf16_t)f.w };
        *reinterpret_cast<bf16x4*>(&Alds[swz(row, (c0 + j * 4) * 2)]) = o;
      }
    } else {
      const int row = t >> 1, cb0 = (t & 1) * 64;
      const bf16_t* src = A + (size_t)(m0 + row) * K + k0 + cb0 / 2;
      #pragma unroll
      for (int i = 0; i < 4; ++i)
        *reinterpret_cast<bf16x8*>(&Alds[swz(row, cb0 + 16 * i)]) =
            *reinterpret_cast<const bf16x8*>(src + 8 * i);
    }
    // stage W tile [64 n][64 k] — proven vector pattern
    {
      const int row = t >> 2, cb = ((2 * t) & 7) * 16;
      const bf16_t* src = Wt + (size_t)(n0 + row) * K + k0 + cb / 2;
      *reinterpret_cast<bf16x8*>(&Wlds[swz(row, cb)]) = *reinterpret_cast<const bf16x8*>(src);
      *reinterpret_cast<bf16x8*>(&Wlds[swz(row, cb + 16)]) = *reinterpret_cast<const bf16x8*>(src + 8);
    }
    __syncthreads();
    #pragma unroll
    for (int ks = 0; ks < 2; ++ks) {
      const int kb = (ks * 32 + ((l >> 4) * 8)) * 2;
      bf16x8 af[2];
      #pragma unroll
      for (int mi = 0; mi < 2; ++mi)
        af[mi] = *reinterpret_cast<const bf16x8*>(
            &Alds[swz(w * 32 + mi * 16 + (l & 15), kb)]);
      #pragma unroll
      for (int ct = 0; ct < 4; ++ct) {
        bf16x8 bfr = *reinterpret_cast<const bf16x8*>(&Wlds[swz(ct * 16 + (l & 15), kb)]);
        acc[0][ct] = mfma16(af[0], bfr, acc[0][ct]);
        acc[1][ct] = mfma16(af[1], bfr, acc[1][ct]);
      }
    }
  }
  #pragma unroll
  for (int mi = 0; mi < 2; ++mi) {
    #pragma unroll
    for (int ct = 0; ct < 4; ++ct) {
      const int col = n0 + ct * 16 + (l & 15);
      const float bv = bias[col];
      #pragma unroll
      for (int r = 0; r < 4; ++r) {
        const int row = m0 + w * 32 + mi * 16 + ((l >> 4) * 4) + r;
        float x = acc[mi][ct][r] + bv;
        if constexpr (RELU) x = fmaxf(x, 0.f);
        C[(size_t)row * N + col] = (OT)(x * postscale);
      }
    }
  }
}

// ------- merged K+V projection v3 (BM=128); V written TRANSPOSED ------------
__global__ __launch_bounds__(256)
void gemm_kv(const float* __restrict__ A, const bf16_t* __restrict__ Wtk,
             const bf16_t* __restrict__ Wtv, const float* __restrict__ bk,
             const float* __restrict__ bv, bf16_t* __restrict__ Ck,
             bf16_t* __restrict__ Vt)
{
  constexpr int K = 256, N = 512;
  __shared__ alignas(16) char Alds[128 * 128];   // 16 KB
  __shared__ alignas(16) char Wk_lds[64 * 128];  //  8 KB
  __shared__ alignas(16) char Wv_lds[64 * 128];  //  8 KB
  const int t = threadIdx.x;
  const int l = t & 63, w = t >> 6;
  const int xcd = blockIdx.x & 7, idx = blockIdx.x >> 3;
  const int m0 = (xcd * 8 + (idx >> 3)) * 128, n0 = (idx & 7) * 64;

  f32x4 acck[2][4] = {}, accv[2][4] = {};
  for (int k0 = 0; k0 < K; k0 += 64) {
    __syncthreads();
    {
      const int row = t >> 1, c0 = (t & 1) * 32;
      const float4* ap = reinterpret_cast<const float4*>(A + (size_t)(m0 + row) * K + k0 + c0);
      #pragma unroll
      for (int j = 0; j < 8; ++j) {
        float4 f = ap[j];
        bf16x4 o = { (bf16_t)f.x, (bf16_t)f.y, (bf16_t)f.z, (bf16_t)f.w };
        *reinterpret_cast<bf16x4*>(&Alds[swz(row, (c0 + j * 4) * 2)]) = o;
      }
    }
    {
      const int row = t >> 2, cb = ((2 * t) & 7) * 16;
      const bf16_t* sk = Wtk + (size_t)(n0 + row) * K + k0 + cb / 2;
      const bf16_t* sv = Wtv + (size_t)(n0 + row) * K + k0 + cb / 2;
      *reinterpret_cast<bf16x8*>(&Wk_lds[swz(row, cb)]) = *reinterpret_cast<const bf16x8*>(sk);
      *reinterpret_cast<bf16x8*>(&Wk_lds[swz(row, cb + 16)]) = *reinterpret_cast<const bf16x8*>(sk + 8);
      *reinterpret_cast<bf16x8*>(&Wv_lds[swz(row, cb)]) = *reinterpret_cast<const bf16x8*>(sv);
      *reinterpret_cast<bf16x8*>(&Wv_lds[swz(row, cb + 16)]) = *reinterpret_cast<const bf16x8*>(sv + 8);
    }
    __syncthreads();
    #pragma unroll
    for (int ks = 0; ks < 2; ++ks) {
      const int kb = (ks * 32 + ((l >> 4) * 8)) * 2;
      bf16x8 af[2];
      #pragma unroll
      for (int mi = 0; mi < 2; ++mi)
        af[mi] = *reinterpret_cast<const bf16x8*>(
            &Alds[swz(w * 32 + mi * 16 + (l & 15), kb)]);
      #pragma unroll
      for (int ct = 0; ct < 4; ++ct) {
        bf16x8 bk8 = *reinterpret_cast<const bf16x8*>(&Wk_lds[swz(ct * 16 + (l & 15), kb)]);
        bf16x8 bv8 = *reinterpret_cast<const bf16x8*>(&Wv_lds[swz(ct * 16 + (l & 15), kb)]);
        acck[0][ct] = mfma16(af[0], bk8, acck[0][ct]);
        acck[1][ct] = mfma16(af[1], bk8, acck[1][ct]);
        accv[0][ct] = mfma16(af[0], bv8, accv[0][ct]);
        accv[1][ct] = mfma16(af[1], bv8, accv[1][ct]);
      }
    }
  }
  #pragma unroll
  for (int mi = 0; mi < 2; ++mi) {
    const int row0 = m0 + w * 32 + mi * 16 + ((l >> 4) * 4);   // 4 consecutive kv
    const int vb = row0 >> 10;
    const int kv = row0 & 1023;
    #pragma unroll
    for (int ct = 0; ct < 4; ++ct) {
      const int col = n0 + ct * 16 + (l & 15);
      const float bkv = bk[col], bvv = bv[col];
      #pragma unroll
      for (int r = 0; r < 4; ++r)
        Ck[(size_t)(row0 + r) * N + col] = (bf16_t)(fmaxf(acck[mi][ct][r] + bkv, 0.f) * KSCALE);
      bf16x4 vv;
      #pragma unroll
      for (int r = 0; r < 4; ++r) vv[r] = (bf16_t)fmaxf(accv[mi][ct][r] + bvv, 0.f);
      bf16_t* dst = Vt + (((size_t)vb * NH + (col >> 6)) * DKH + (col & 63)) * LKk + kv;
      *reinterpret_cast<bf16x4*>(dst) = vv;
    }
  }
}

// -- flash attention: R14-verified (unchanged this round) --------------------
__global__ __launch_bounds__(256)
void attn_kernel(const bf16_t* __restrict__ Qp, const bf16_t* __restrict__ Kp,
                 const bf16_t* __restrict__ Vt, const unsigned long long* __restrict__ Mpk,
                 bf16_t* __restrict__ AO)
{
  __shared__ alignas(16) char Klds[64 * 128];
  __shared__ alignas(16) char Vlds[64 * 128];
  __shared__ alignas(16) char Plds[4 * 32 * 128];
  const int t = threadIdx.x, l = t & 63, w = t >> 6;
  const int g = l >> 4, qh = l & 15;
  const int bid = (blockIdx.x & 7) * 64 + (blockIdx.x >> 3);
  const int qt = bid & 7, h = (bid >> 3) & 7, b = bid >> 6;
  const int wq0 = qt * 128 + w * 32;
  const size_t rb = (size_t)b * LQ;
  const bf16_t* vtb = Vt + ((size_t)b * NH + h) * DKH * LKk;

  bf16x8 qf[2][2];
  #pragma unroll
  for (int j = 0; j < 2; ++j)
    #pragma unroll
    for (int ks = 0; ks < 2; ++ks)
      qf[j][ks] = *reinterpret_cast<const bf16x8*>(
          Qp + (rb + wq0 + j * 16 + qh) * DMODEL + h * DKH + ks * 32 + g * 8);

  const unsigned long long* mrow0 = Mpk + (rb + wq0 + qh) * (LKk / 64);
  const unsigned long long* mrow1 = Mpk + (rb + wq0 + 16 + qh) * (LKk / 64);

  f32x4 acc[2][4] = {};
  float mrun[2] = { -1e30f, -1e30f }, lsum[2] = { 0.f, 0.f };

  for (int kv0 = 0; kv0 < LKk; kv0 += 64) {
    const unsigned long long mw[2] = { mrow0[kv0 >> 6], mrow1[kv0 >> 6] };

    __syncthreads();
    {
      const int row = t >> 2, cb = ((2 * t) & 7) * 16;
      const bf16_t* src = Kp + (rb + kv0 + row) * DMODEL + h * DKH + cb / 2;
      *reinterpret_cast<bf16x8*>(&Klds[swz(row, cb)]) = *reinterpret_cast<const bf16x8*>(src);
      *reinterpret_cast<bf16x8*>(&Klds[swz(row, cb + 16)]) = *reinterpret_cast<const bf16x8*>(src + 8);
    }
    {
      const int row = t >> 2, cb = ((2 * t) & 7) * 16;
      const bf16_t* src = vtb + (size_t)row * LKk + kv0 + cb / 2;
      *reinterpret_cast<bf16x8*>(&Vlds[swz(row, cb)]) = *reinterpret_cast<const bf16x8*>(src);
      *reinterpret_cast<bf16x8*>(&Vlds[swz(row, cb + 16)]) = *reinterpret_cast<const bf16x8*>(src + 8);
    }
    __syncthreads();

    f32x4 s[2][4] = {};
    #pragma unroll
    for (int ks = 0; ks < 2; ++ks) {
      const int kb = (ks * 32 + g * 8) * 2;
      #pragma unroll
      for (int ct = 0; ct < 4; ++ct) {
        bf16x8 kf = *reinterpret_cast<const bf16x8*>(&Klds[swz(ct * 16 + qh, kb)]);
        s[0][ct] = mfma16(kf, qf[0][ks], s[0][ct]);
        s[1][ct] = mfma16(kf, qf[1][ks], s[1][ct]);
      }
    }

    #pragma unroll
    for (int j = 0; j < 2; ++j) {
      float rmax = -1e30f;
      #pragma unroll
      for (int ct = 0; ct < 4; ++ct) {
        #pragma unroll
        for (int r = 0; r < 4; ++r) {
          float x = ((mw[j] >> (ct * 16 + g * 4 + r)) & 1) ? s[j][ct][r] : -1e8f;
          s[j][ct][r] = x;
          rmax = fmaxf(rmax, x);
        }
      }
      rmax = fmaxf(rmax, __shfl_xor(rmax, 16));
      rmax = fmaxf(rmax, __shfl_xor(rmax, 32));
      const float newm = fmaxf(mrun[j], rmax);

      if (__any(newm > mrun[j])) {
        const float scale = __builtin_amdgcn_exp2f(mrun[j] - newm);
        lsum[j] *= scale;
        #pragma unroll
        for (int r = 0; r < 4; ++r) {
          const float sr = __shfl(scale, g * 4 + r, 64);
          #pragma unroll
          for (int dct = 0; dct < 4; ++dct) acc[j][dct][r] *= sr;
        }
        mrun[j] = newm;
      }

      float psum = 0.f;
      #pragma unroll
      for (int ct = 0; ct < 4; ++ct) {
        #pragma unroll
        for (int r = 0; r < 4; ++r) {
          const float pv = __builtin_amdgcn_exp2f(s[j][ct][r] - mrun[j]);
          s[j][ct][r] = pv;
          psum += pv;
        }
      }
      psum += __shfl_xor(psum, 16);
      psum += __shfl_xor(psum, 32);
      lsum[j] += psum;

      #pragma unroll
      for (int ct = 0; ct < 4; ++ct) {
        #pragma unroll
        for (int r = 0; r < 4; ++r)
          *reinterpret_cast<bf16_t*>(
              &Plds[w * 4096 + swz(j * 16 + qh, (ct * 16 + g * 4 + r) * 2)]) =
              (bf16_t)s[j][ct][r];
      }
    }

    #pragma unroll
    for (int ks = 0; ks < 2; ++ks) {
      const int kb = (ks * 32 + g * 8) * 2;
      bf16x8 pf0 = *reinterpret_cast<const bf16x8*>(&Plds[w * 4096 + swz(qh, kb)]);
      bf16x8 pf1 = *reinterpret_cast<const bf16x8*>(&Plds[w * 4096 + swz(16 + qh, kb)]);
      #pragma unroll
      for (int dct = 0; dct < 4; ++dct) {
        bf16x8 vf = *reinterpret_cast<const bf16x8*>(&Vlds[swz(dct * 16 + qh, kb)]);
        acc[0][dct] = mfma16(pf0, vf, acc[0][dct]);
        acc[1][dct] = mfma16(pf1, vf, acc[1][dct]);
      }
    }
  }

  #pragma unroll
  for (int j = 0; j < 2; ++j) {
    const float inv = 1.0f / lsum[j];
    float invr[4];
    #pragma unroll
    for (int r = 0; r < 4; ++r) invr[r] = __shfl(inv, g * 4 + r, 64);
    #pragma unroll
    for (int dct = 0; dct < 4; ++dct) {
      const int col = h * DKH + dct * 16 + qh;
      #pragma unroll
      for (int r = 0; r < 4; ++r) {
        const int q = wq0 + j * 16 + g * 4 + r;
        AO[(rb + q) * DMODEL + col] = (bf16_t)(acc[j][dct][r] * invr[r]);
      }
    }
  }
}

extern "C" void kernel_launch(void* const* d_in, const int* in_sizes, int n_in,
                              void* d_out, int out_size, void* d_ws, size_t ws_size,
                              hipStream_t stream)
{
  const float* query = (const float*)d_in[0];
  const float* keyin = (const float*)d_in[1];
  const int*   mask  = (const int*)d_in[2];
  const float* Wq = (const float*)d_in[3];
  const float* bq = (const float*)d_in[4];
  const float* Wk = (const float*)d_in[5];
  const float* bk = (const float*)d_in[6];
  const float* Wv = (const float*)d_in[7];
  const float* bv = (const float*)d_in[8];
  const float* Wo = (const float*)d_in[9];
  const float* bo = (const float*)d_in[10];
  float* out = (float*)d_out;

  bf16_t* Qp = (bf16_t*)d_ws;
  bf16_t* Kp = Qp + (size_t)MROWS * DMODEL;
  bf16_t* Vt = Kp + (size_t)MROWS * DMODEL;
  bf16_t* AO = Vt + (size_t)MROWS * DMODEL;
  unsigned long long* Mpk = (unsigned long long*)(AO + (size_t)MROWS * DMODEL);
  bf16_t* Wtq = (bf16_t*)(Mpk + MWORDS);
  bf16_t* Wtk = Wtq + 512 * 256;
  bf16_t* Wtv = Wtk + 512 * 256;
  bf16_t* Wto = Wtv + 512 * 256;

  dim3 blk(256);

  weight_prep<<<dim3(160), blk, 0, stream>>>(Wq, Wk, Wv, Wo, Wtq, Wtk, Wtv, Wto);
  mask_pack<<<dim3(MWORDS / 256), blk, 0, stream>>>(mask, Mpk);
  gemm_bias_act<256, true, float, bf16_t><<<dim3(512), blk, 0, stream>>>(query, Wtq, bq, Qp, 1.0f);
  gemm_kv<<<dim3(512), blk, 0, stream>>>(keyin, Wtk, Wtv, bk, bv, Kp, Vt);

  attn_kernel<<<dim3(NB * NH * (LQ / 128)), blk, 0, stream>>>(Qp, Kp, Vt, Mpk, AO);

  gemm_bias_act<512, false, bf16_t, float><<<dim3(512), blk, 0, stream>>>(AO, Wto, bo, out, 1.0f);
}